// Round 10
// baseline (149257.361 us; speedup 1.0000x reference)
//
#include <hip/hip_runtime.h>
#include <hip/hip_cooperative_groups.h>
#include <math.h>

namespace cg = cooperative_groups;

#define T_DEC 256

__device__ __forceinline__ float sigf(float x) { return 1.0f / (1.0f + expf(-x)); }

// ---------------- parameter block ----------------
struct P {
    const float *WihA, *WhhA, *bA, *WihD, *WhhD, *bD;
    const float *enc, *pm, *wqT, *Wlc, *Wld, *vatt;
    const float *Wp, *bp, *Wg, *bg;
    const float *inputs, *Wpre1, *Wpre2;
    float *preB0, *preB1;
    float *hA0, *hA1, *cA, *hD0, *hD1, *cD;
    float *aw, *cum, *ctx0, *ctx1;
    float *partA, *partD;
    const int* mlen;
    float *mel, *gate, *align;
};

// ---------------- shared-memory plan (35.9 KB/block) ----------------
struct SH {
    float wlc0[31][32], wlc1[31][32];   // persistent loc-conv weights
    float wlds[128][36];                // persistent loc-dense weights
    float vs[128];                      // persistent v_att
    union {
        struct { float hs[1024]; float red[256]; float pqs[128];
                 float aw0s[288]; float aw1s[288]; float sm[256]; float red4[4]; } a;
        struct { float hc[1536]; float redp[164]; } pr;
        struct { float xs[80]; float h1[256]; } n;
    } u;
};

// ---------------- small prologue kernels ----------------
__global__ void convert_mlen(const void* p, int* out) {
    int b = threadIdx.x;
    const int* pi = (const int*)p;
    const float* pf = (const float*)p;
    __shared__ int mode;
    if (b == 0) {
        int i0 = pi[0], i1 = pi[1];
        float f0 = pf[0];
        if (i0 >= 1 && i0 <= 512 && i1 == 0) mode = 2;
        else if (i0 >= 1 && i0 <= 512) mode = 0;
        else if (f0 >= 1.0f && f0 <= 512.0f) mode = 1;
        else mode = 0;
    }
    __syncthreads();
    int v;
    if (mode == 2)      v = pi[2 * b];
    else if (mode == 1) v = (int)(pf[b] + 0.5f);
    else                v = pi[b];
    if (v < 1) v = 1;
    if (v > 256) v = 256;
    out[b] = v;
}

__global__ void zero_f(float* __restrict__ p, int n) {
    int i = blockIdx.x * blockDim.x + threadIdx.x;
    if (i < n) p[i] = 0.0f;
}

__global__ __launch_bounds__(128) void proc_mem(const float* __restrict__ mem,
                                                const float* __restrict__ Wm,
                                                float* __restrict__ pm) {
    int r = blockIdx.x;
    int d = threadIdx.x;
    __shared__ float xs[512];
    for (int k = d; k < 512; k += 128) xs[k] = mem[(size_t)r * 512 + k];
    __syncthreads();
    const float* wr = Wm + (size_t)d * 512;
    float s = 0.f;
    for (int k = 0; k < 512; k += 4) {
        float4 w = *reinterpret_cast<const float4*>(wr + k);
        s = fmaf(xs[k], w.x, s); s = fmaf(xs[k+1], w.y, s);
        s = fmaf(xs[k+2], w.z, s); s = fmaf(xs[k+3], w.w, s);
    }
    pm[(size_t)r * 128 + d] = s;
}

__global__ __launch_bounds__(256) void transpose_wq(const float* __restrict__ Wq,
                                                    float* __restrict__ wqT) {
    int i = blockIdx.x * 256 + threadIdx.x;
    int d = i & 127, k = i >> 7;
    wqT[i] = Wq[(size_t)d * 1024 + k];
}

// ---------------- GEMM core (register-tiled, LDS-free) ----------------
__device__ __forceinline__ void gemm_region(
    const float* __restrict__ xbase, int xstr,
    const float* __restrict__ wbase, int wstr, int wc0,
    int g0, int g1, int kb, int ke,
    int b0, int r0, float acc[2][8])
{
    int lo = kb > g0 ? kb : g0;
    int hi = ke < g1 ? ke : g1;
    if (lo >= hi) return;
    const float* xp0 = xbase + (size_t)b0 * xstr + (lo - g0);
    const float* xp1 = xp0 + xstr;
    const float* wp[8];
    #pragma unroll
    for (int j = 0; j < 8; ++j)
        wp[j] = wbase + (size_t)(r0 + j) * wstr + (lo - wc0);
    for (int k = lo; k < hi; k += 4) {
        float4 xa = *reinterpret_cast<const float4*>(xp0); xp0 += 4;
        float4 xb = *reinterpret_cast<const float4*>(xp1); xp1 += 4;
        #pragma unroll
        for (int j = 0; j < 8; ++j) {
            float4 w = *reinterpret_cast<const float4*>(wp[j]); wp[j] += 4;
            acc[0][j] = fmaf(xa.x, w.x, fmaf(xa.y, w.y, fmaf(xa.z, w.z, fmaf(xa.w, w.w, acc[0][j]))));
            acc[1][j] = fmaf(xb.x, w.x, fmaf(xb.y, w.y, fmaf(xb.z, w.z, fmaf(xb.w, w.w, acc[1][j]))));
        }
    }
}

// ---------------- phase 1: both z-GEMMs (1024 vblocks of 128 threads) ------
__device__ void phase1(const P& p, int t) {
    bool do_a = (t < 255), do_d = (t >= 0);
    int pc = t & 1, pn = (t + 1) & 1;
    const float* hAc  = pc ? p.hA1 : p.hA0;     // h_a(t)
    const float* hDp  = pn ? p.hD1 : p.hD0;     // h_d(t-1)
    const float* ctxc = pc ? p.ctx1 : p.ctx0;   // ctx(t)
    const float* preT = pn ? p.preB1 : p.preB0; // pre(t+1)
    int vb = blockIdx.x * 2 + (threadIdx.x >> 7);
    int vt = threadIdx.x & 127;
    int b0 = (vt & 15) * 2, rq = vt >> 4;
    float acc[2][8];
    #pragma unroll
    for (int i = 0; i < 2; ++i)
        #pragma unroll
        for (int j = 0; j < 8; ++j) acc[i][j] = 0.f;
    float* q;
    if (vb < 384) {
        if (!do_a) return;
        int rt = vb / 6, ks = vb % 6;
        int kb = ks * 300, ke = kb + 300; if (ke > 1792) ke = 1792;
        int r0 = rt * 64 + rq * 8;
        gemm_region(preT, 256,  p.WihA, 768, 0,     0,    256,  kb, ke, b0, r0, acc);
        gemm_region(ctxc, 512,  p.WihA, 768, 0,     256,  768,  kb, ke, b0, r0, acc);
        gemm_region(hAc,  1024, p.WhhA, 1024, 768,  768,  1792, kb, ke, b0, r0, acc);
        q = p.partA + ((size_t)(ks * 32 + b0) * 4096 + r0);
    } else {
        if (!do_d) return;
        int v2 = vb - 384;
        int rt = v2 / 10, ks = v2 % 10;
        int kb = ks * 256, ke = kb + 256;
        int r0 = rt * 64 + rq * 8;
        gemm_region(hAc,  1024, p.WihD, 1536, 0,     0,    1024, kb, ke, b0, r0, acc);
        gemm_region(ctxc, 512,  p.WihD, 1536, 0,     1024, 1536, kb, ke, b0, r0, acc);
        gemm_region(hDp,  1024, p.WhhD, 1024, 1536,  1536, 2560, kb, ke, b0, r0, acc);
        q = p.partD + ((size_t)(ks * 32 + b0) * 4096 + r0);
    }
    *reinterpret_cast<float4*>(q)     = make_float4(acc[0][0], acc[0][1], acc[0][2], acc[0][3]);
    *reinterpret_cast<float4*>(q + 4) = make_float4(acc[0][4], acc[0][5], acc[0][6], acc[0][7]);
    float* q1 = q + 4096;
    *reinterpret_cast<float4*>(q1)     = make_float4(acc[1][0], acc[1][1], acc[1][2], acc[1][3]);
    *reinterpret_cast<float4*>(q1 + 4) = make_float4(acc[1][4], acc[1][5], acc[1][6], acc[1][7]);
}

// ---------------- attn weight staging (persistent LDS, blocks 32..63) ------
__device__ void stage_attn(const P& p, SH* sh) {
    int tid = threadIdx.x;
    for (int i = tid; i < 992; i += 256) {
        int k = i >> 5, f = i & 31;
        sh->wlc0[k][f] = p.Wlc[(size_t)f * 62 + k];
        sh->wlc1[k][f] = p.Wlc[(size_t)f * 62 + 31 + k];
    }
    for (int i = tid; i < 4096; i += 256) sh->wlds[i >> 5][i & 31] = p.Wld[i];
    if (tid < 128) sh->vs[tid] = p.vatt[tid];
    __syncthreads();
}

// ---------------- phase 3: gates + proj | gates + attn | prenet ------------
__device__ void phase3(const P& p, SH* sh, int t) {
    const int tid = threadIdx.x;
    const int blk = blockIdx.x;
    int pc = t & 1, pn = (t + 1) & 1;
    if (blk < 32) {
        // ---- D-gates + proj(t) ----
        if (t < 0) return;
        int b = blk;
        float* hDn = pc ? p.hD1 : p.hD0;
        const float* ctxc = pc ? p.ctx1 : p.ctx0;
        for (int j = 0; j < 4; ++j) {
            int u = tid + (j << 8);
            float z[4];
            #pragma unroll
            for (int g2 = 0; g2 < 4; ++g2) {
                float s = p.bD[g2 * 1024 + u];
                #pragma unroll
                for (int ks = 0; ks < 10; ++ks)
                    s += p.partD[(size_t)(ks * 32 + b) * 4096 + g2 * 1024 + u];
                z[g2] = s;
            }
            int idx = b * 1024 + u;
            float cn = sigf(z[1]) * p.cD[idx] + sigf(z[0]) * tanhf(z[2]);
            float hn = sigf(z[3]) * tanhf(cn);
            p.cD[idx] = cn; hDn[idx] = hn; sh->u.pr.hc[u] = hn;
        }
        for (int k = tid; k < 512; k += 256) sh->u.pr.hc[1024 + k] = ctxc[(size_t)b * 512 + k];
        __syncthreads();
        if (tid < 162) {
            int o = tid >> 1, hf = tid & 1;
            const float* wr = (o < 80) ? (p.Wp + (size_t)o * 1536) : p.Wg;
            float s = 0.f;
            int k0 = hf * 768;
            for (int k = k0; k < k0 + 768; k += 4) {
                float4 w = *reinterpret_cast<const float4*>(wr + k);
                s = fmaf(sh->u.pr.hc[k], w.x, s);   s = fmaf(sh->u.pr.hc[k+1], w.y, s);
                s = fmaf(sh->u.pr.hc[k+2], w.z, s); s = fmaf(sh->u.pr.hc[k+3], w.w, s);
            }
            sh->u.pr.redp[tid] = s;
        }
        __syncthreads();
        if (tid < 81) {
            float s = sh->u.pr.redp[2 * tid] + sh->u.pr.redp[2 * tid + 1];
            if (tid < 80) p.mel[((size_t)b * T_DEC + t) * 80 + tid] = s + p.bp[tid];
            else          p.gate[(size_t)b * T_DEC + t] = s + p.bg[0];
        }
    } else if (blk < 64) {
        // ---- A-gates + attn(t+1) ----
        if (t < -1 || t >= 255) return;
        int b = blk - 32, tt = t + 1;
        float* hAn  = pn ? p.hA1 : p.hA0;
        float* ctxn = pn ? p.ctx1 : p.ctx0;
        for (int j = 0; j < 4; ++j) {
            int u = tid + (j << 8);
            float z[4];
            #pragma unroll
            for (int g2 = 0; g2 < 4; ++g2) {
                float s = p.bA[g2 * 1024 + u];
                #pragma unroll
                for (int ks = 0; ks < 6; ++ks)
                    s += p.partA[(size_t)(ks * 32 + b) * 4096 + g2 * 1024 + u];
                z[g2] = s;
            }
            int idx = b * 1024 + u;
            float cn = sigf(z[1]) * p.cA[idx] + sigf(z[0]) * tanhf(z[2]);
            float hn = sigf(z[3]) * tanhf(cn);
            p.cA[idx] = cn; hAn[idx] = hn; sh->u.a.hs[u] = hn;
        }
        for (int i = tid; i < 288; i += 256) {
            int pos = i - 16;
            float v0 = 0.f, v1 = 0.f;
            if (pos >= 0 && pos < 256) {
                v0 = p.aw[(size_t)b * 256 + pos];
                v1 = p.cum[(size_t)b * 256 + pos];
            }
            sh->u.a.aw0s[i] = v0; sh->u.a.aw1s[i] = v1;
        }
        __syncthreads();
        {
            int d = tid & 127, hf = tid >> 7;
            float s = 0.f;
            int k0 = hf * 512;
            for (int k = k0; k < k0 + 512; ++k)
                s = fmaf(sh->u.a.hs[k], p.wqT[(size_t)k * 128 + d], s);
            sh->u.a.red[tid] = s;
        }
        __syncthreads();
        if (tid < 128) sh->u.a.pqs[tid] = sh->u.a.red[tid] + sh->u.a.red[tid + 128];
        __syncthreads();
        float cf[32];
        #pragma unroll
        for (int f = 0; f < 32; ++f) cf[f] = 0.f;
        for (int k = 0; k < 31; ++k) {
            float a0 = sh->u.a.aw0s[tid + 1 + k], a1 = sh->u.a.aw1s[tid + 1 + k];
            #pragma unroll
            for (int fq = 0; fq < 8; ++fq) {
                float4 w0 = *reinterpret_cast<const float4*>(&sh->wlc0[k][fq << 2]);
                float4 w1 = *reinterpret_cast<const float4*>(&sh->wlc1[k][fq << 2]);
                cf[fq*4+0] = fmaf(a0, w0.x, fmaf(a1, w1.x, cf[fq*4+0]));
                cf[fq*4+1] = fmaf(a0, w0.y, fmaf(a1, w1.y, cf[fq*4+1]));
                cf[fq*4+2] = fmaf(a0, w0.z, fmaf(a1, w1.z, cf[fq*4+2]));
                cf[fq*4+3] = fmaf(a0, w0.w, fmaf(a1, w1.w, cf[fq*4+3]));
            }
        }
        float e = 0.f;
        {
            const float* pmr = p.pm + ((size_t)b * 256 + tid) * 128;
            for (int d = 0; d < 128; ++d) {
                float loc = 0.f;
                #pragma unroll
                for (int fq = 0; fq < 8; ++fq) {
                    float4 w = *reinterpret_cast<const float4*>(&sh->wlds[d][fq << 2]);
                    loc = fmaf(cf[fq*4+0], w.x, loc); loc = fmaf(cf[fq*4+1], w.y, loc);
                    loc = fmaf(cf[fq*4+2], w.z, loc); loc = fmaf(cf[fq*4+3], w.w, loc);
                }
                float a = tanhf(sh->u.a.pqs[d] + loc + pmr[d]);
                e = fmaf(a, sh->vs[d], e);
            }
        }
        if (tid >= p.mlen[b]) e = -1e9f;
        float m = e;
        #pragma unroll
        for (int o2 = 32; o2 >= 1; o2 >>= 1) m = fmaxf(m, __shfl_xor(m, o2));
        if ((tid & 63) == 0) sh->u.a.red4[tid >> 6] = m;
        __syncthreads();
        m = fmaxf(fmaxf(sh->u.a.red4[0], sh->u.a.red4[1]),
                  fmaxf(sh->u.a.red4[2], sh->u.a.red4[3]));
        __syncthreads();
        float pe = expf(e - m);
        float s = pe;
        #pragma unroll
        for (int o2 = 32; o2 >= 1; o2 >>= 1) s += __shfl_xor(s, o2);
        if ((tid & 63) == 0) sh->u.a.red4[tid >> 6] = s;
        __syncthreads();
        s = sh->u.a.red4[0] + sh->u.a.red4[1] + sh->u.a.red4[2] + sh->u.a.red4[3];
        float w = pe / s;
        sh->u.a.sm[tid] = w;
        p.aw[(size_t)b * 256 + tid] = w;
        p.cum[(size_t)b * 256 + tid] += w;
        p.align[((size_t)b * T_DEC + tt) * 256 + tid] = w;
        __syncthreads();
        for (int d = tid; d < 512; d += 256) {
            const float* mb = p.enc + (size_t)b * 131072 + d;
            float s2 = 0.f;
            for (int q2 = 0; q2 < 256; ++q2) s2 = fmaf(sh->u.a.sm[q2], mb[(size_t)q2 * 512], s2);
            ctxn[(size_t)b * 512 + d] = s2;
        }
    } else if (blk < 96) {
        // ---- prenet(t+2) ----
        int ts = t + 2;
        if (ts > 255) return;
        int b = blk - 64;
        float* dst = (ts & 1) ? p.preB1 : p.preB0;
        if (tid < 80) sh->u.n.xs[tid] = (ts == 0) ? 0.0f
                        : p.inputs[((size_t)b * T_DEC + (ts - 1)) * 80 + tid];
        __syncthreads();
        {
            const float* wr = p.Wpre1 + (size_t)tid * 80;
            float s = 0.f;
            #pragma unroll 8
            for (int k = 0; k < 80; ++k) s = fmaf(sh->u.n.xs[k], wr[k], s);
            sh->u.n.h1[tid] = fmaxf(s, 0.0f);
        }
        __syncthreads();
        {
            const float* wr = p.Wpre2 + (size_t)tid * 256;
            float s = 0.f;
            for (int k = 0; k < 256; k += 4) {
                float4 w = *reinterpret_cast<const float4*>(wr + k);
                s = fmaf(sh->u.n.h1[k], w.x, s);   s = fmaf(sh->u.n.h1[k+1], w.y, s);
                s = fmaf(sh->u.n.h1[k+2], w.z, s); s = fmaf(sh->u.n.h1[k+3], w.w, s);
            }
            dst[(size_t)b * 256 + tid] = fmaxf(s, 0.0f);
        }
    }
}

// ---------------- persistent cooperative kernel ----------------
__global__ __launch_bounds__(256, 2) void coop_main(P p) {
    cg::grid_group g = cg::this_grid();
    __shared__ SH sh;
    if (blockIdx.x >= 32 && blockIdx.x < 64) stage_attn(p, &sh);
    phase3(p, &sh, -2);           // prenet(0) only
    g.sync();
    for (int t = -1; t <= 255; ++t) {
        phase1(p, t);
        g.sync();
        phase3(p, &sh, t);
        g.sync();
    }
}

// ---------------- fallback (non-cooperative) ----------------
__global__ __launch_bounds__(256, 2) void fb1(P p, int t) { phase1(p, t); }
__global__ __launch_bounds__(256) void fb3(P p, int t) {
    __shared__ SH sh;
    if (blockIdx.x >= 32 && blockIdx.x < 64) stage_attn(p, &sh);
    phase3(p, &sh, t);
}

// ---------------- host ----------------
extern "C" void kernel_launch(void* const* d_in, const int* in_sizes, int n_in,
                              void* d_out, int out_size, void* d_ws, size_t ws_size,
                              hipStream_t stream) {
    const float* enc    = (const float*)d_in[0];
    const float* inputs = (const float*)d_in[1];
    const void*  mlraw  = d_in[2];
    const float* W_pre1 = (const float*)d_in[3];
    const float* W_pre2 = (const float*)d_in[4];
    const float* Wih_a  = (const float*)d_in[5];
    const float* Whh_a  = (const float*)d_in[6];
    const float* b_a    = (const float*)d_in[7];
    const float* W_q    = (const float*)d_in[8];
    const float* W_mem  = (const float*)d_in[9];
    const float* Wlc    = (const float*)d_in[10];
    const float* Wld    = (const float*)d_in[11];
    const float* v_att  = (const float*)d_in[12];
    const float* Wih_d  = (const float*)d_in[13];
    const float* Whh_d  = (const float*)d_in[14];
    const float* b_d    = (const float*)d_in[15];
    const float* W_proj = (const float*)d_in[16];
    const float* b_proj = (const float*)d_in[17];
    const float* W_gate = (const float*)d_in[18];
    const float* b_gate = (const float*)d_in[19];

    float* ws = (float*)d_ws;
    size_t o = 0;
    float* pm    = ws + o; o += 1048576;
    float* wqT   = ws + o; o += 131072;
    float* preB0 = ws + o; o += 8192;
    float* preB1 = ws + o; o += 8192;
    size_t zs0 = o;
    float* hA0 = ws + o; o += 32768;
    float* hA1 = ws + o; o += 32768;
    float* cA  = ws + o; o += 32768;
    float* hD0 = ws + o; o += 32768;
    float* hD1 = ws + o; o += 32768;
    float* cD  = ws + o; o += 32768;
    float* aw  = ws + o; o += 8192;
    float* cum = ws + o; o += 8192;
    float* ctx0 = ws + o; o += 16384;
    float* ctx1 = ws + o; o += 16384;
    int zlen = (int)(o - zs0);                 // 245760
    float* partA = ws + o; o += 6 * 32 * 4096;    // 786432
    float* partD = ws + o; o += 10 * 32 * 4096;   // 1310720
    int* mlen = (int*)(ws + o); o += 32;
    if (ws_size < o * 4) return;               // diagnostic: 0.1455 signature

    float* out       = (float*)d_out;
    float* mel_out   = out;
    float* gate_out  = out + (size_t)32 * 256 * 80;
    float* align_out = gate_out + (size_t)32 * 256;

    // prologue (4 nodes)
    convert_mlen<<<1, 32, 0, stream>>>(mlraw, mlen);
    proc_mem<<<8192, 128, 0, stream>>>(enc, W_mem, pm);
    transpose_wq<<<512, 256, 0, stream>>>(W_q, wqT);
    zero_f<<<(zlen + 255) / 256, 256, 0, stream>>>(ws + zs0, zlen);

    P pv;
    pv.WihA = Wih_a; pv.WhhA = Whh_a; pv.bA = b_a;
    pv.WihD = Wih_d; pv.WhhD = Whh_d; pv.bD = b_d;
    pv.enc = enc; pv.pm = pm; pv.wqT = wqT;
    pv.Wlc = Wlc; pv.Wld = Wld; pv.vatt = v_att;
    pv.Wp = W_proj; pv.bp = b_proj; pv.Wg = W_gate; pv.bg = b_gate;
    pv.inputs = inputs; pv.Wpre1 = W_pre1; pv.Wpre2 = W_pre2;
    pv.preB0 = preB0; pv.preB1 = preB1;
    pv.hA0 = hA0; pv.hA1 = hA1; pv.cA = cA;
    pv.hD0 = hD0; pv.hD1 = hD1; pv.cD = cD;
    pv.aw = aw; pv.cum = cum; pv.ctx0 = ctx0; pv.ctx1 = ctx1;
    pv.partA = partA; pv.partD = partD;
    pv.mlen = mlen;
    pv.mel = mel_out; pv.gate = gate_out; pv.align = align_out;

    void* args[] = { &pv };
    hipError_t e = hipLaunchCooperativeKernel((const void*)coop_main,
                                              dim3(512), dim3(256), args, 0, stream);
    if (e != hipSuccess) {
        // fallback: same phases as discrete launches
        fb3<<<96, 256, 0, stream>>>(pv, -2);
        for (int t = -1; t <= 255; ++t) {
            fb1<<<512, 256, 0, stream>>>(pv, t);
            fb3<<<96, 256, 0, stream>>>(pv, t);
        }
    }
}

// Round 12
// 118452.283 us; speedup vs baseline: 1.2601x; 1.2601x over previous
//
#include <hip/hip_runtime.h>
#include <hip/hip_cooperative_groups.h>
#include <math.h>

namespace cg = cooperative_groups;

#define T_DEC 256
// GEMM geometry
#define AKSEG 256
#define ANC 8
#define NKA 7
#define DKSEG 320
#define DNC 10
#define NKD 8
#define ABLK (32 * NKA)      // 224
#define NBLK (ABLK + 32 * NKD)  // 480

__device__ __forceinline__ float sigf(float x) { return 1.0f / (1.0f + expf(-x)); }

typedef __attribute__((address_space(1))) const void* gas_t;
typedef __attribute__((address_space(3))) void* las_t;
__device__ __forceinline__ void gl_lds16(const float* g, float* l) {
    __builtin_amdgcn_global_load_lds((gas_t)g, (las_t)l, 16, 0, 0);
}

// ---------------- parameter block ----------------
struct P {
    const float *WihA, *WhhA, *bA, *WihD, *WhhD, *bD;
    const float *enc, *pm, *wqT, *Wlc, *Wld, *vatt;
    const float *Wp, *bp, *Wg, *bg;
    const float *inputs, *Wpre1, *Wpre2;
    float *preB0, *preB1;
    float *hA0, *hA1, *cA, *hD0, *hD1, *cD;
    float *aw, *cum, *ctx0, *ctx1;
    float *partA, *partD;
    const int* mlen;
    float *mel, *gate, *align;
};

// ---------------- shared memory union ----------------
struct SHg {                      // phase1 GEMM
    float W[2][4096];             // [buf][128 rows * 32 k]  (xor-swizzled cols)
    float X[2][1056];             // [buf][32 b * 33]
};
struct SHa {                      // phase2 attn
    float wlc0[31][32], wlc1[31][32];
    float wlds[128][36];
    float vs[128];
    float hs[1024];
    float red[256];
    float pqs[128];
    float aw0s[288], aw1s[288];
    float red4[4];
};
struct SHp { float hc[1536]; float redp[164]; };
struct SHn { float xs[80]; float h1[256]; };
struct SHc { float sm[256]; float red[4][64]; };
union SHU { SHg g; SHa a; SHp p; SHn n; SHc c; };

// ---------------- small prologue kernels ----------------
__global__ void convert_mlen(const void* p, int* out) {
    int b = threadIdx.x;
    const int* pi = (const int*)p;
    const float* pf = (const float*)p;
    __shared__ int mode;
    if (b == 0) {
        int i0 = pi[0], i1 = pi[1];
        float f0 = pf[0];
        if (i0 >= 1 && i0 <= 512 && i1 == 0) mode = 2;
        else if (i0 >= 1 && i0 <= 512) mode = 0;
        else if (f0 >= 1.0f && f0 <= 512.0f) mode = 1;
        else mode = 0;
    }
    __syncthreads();
    int v;
    if (mode == 2)      v = pi[2 * b];
    else if (mode == 1) v = (int)(pf[b] + 0.5f);
    else                v = pi[b];
    if (v < 1) v = 1;
    if (v > 256) v = 256;
    out[b] = v;
}

__global__ void zero_f(float* __restrict__ p, int n) {
    int i = blockIdx.x * blockDim.x + threadIdx.x;
    if (i < n) p[i] = 0.0f;
}

__global__ __launch_bounds__(128) void proc_mem(const float* __restrict__ mem,
                                                const float* __restrict__ Wm,
                                                float* __restrict__ pm) {
    int r = blockIdx.x;
    int d = threadIdx.x;
    __shared__ float xs[512];
    for (int k = d; k < 512; k += 128) xs[k] = mem[(size_t)r * 512 + k];
    __syncthreads();
    const float* wr = Wm + (size_t)d * 512;
    float s = 0.f;
    for (int k = 0; k < 512; k += 4) {
        float4 w = *reinterpret_cast<const float4*>(wr + k);
        s = fmaf(xs[k], w.x, s); s = fmaf(xs[k+1], w.y, s);
        s = fmaf(xs[k+2], w.z, s); s = fmaf(xs[k+3], w.w, s);
    }
    pm[(size_t)r * 128 + d] = s;
}

__global__ __launch_bounds__(256) void transpose_wq(const float* __restrict__ Wq,
                                                    float* __restrict__ wqT) {
    int i = blockIdx.x * 256 + threadIdx.x;
    int d = i & 127, k = i >> 7;
    wqT[i] = Wq[(size_t)d * 1024 + k];
}

// ---------------- phase 1: streaming z-GEMMs ----------------
// Block: 256 thr, out-tile 32 b x 128 rows, one k-seg. W via global_load_lds
// (double-buffered LDS, xor-swizzled source cols); X via reg-stage.
__device__ void phase1(const P& p, SHU* sh, int t) {
    const int blk = blockIdx.x;
    const int tid = threadIdx.x;
    const bool isA = blk < ABLK;
    if (isA ? (t >= 255) : (t < 0)) return;
    int pc = t & 1, pn = (t + 1) & 1;
    const float* hAc  = pc ? p.hA1 : p.hA0;     // h_a(t)
    const float* hDp  = pn ? p.hD1 : p.hD0;     // h_d(t-1)
    const float* ctxc = pc ? p.ctx1 : p.ctx0;   // ctx(t)
    const float* preT = pn ? p.preB1 : p.preB0; // pre(t+1)
    int rt, ks, nc, kseg;
    if (isA) { rt = blk / NKA; ks = blk % NKA; nc = ANC; kseg = AKSEG; }
    else     { int bb = blk - ABLK; rt = bb / NKD; ks = bb % NKD; nc = DNC; kseg = DKSEG; }
    const int lane = tid & 63, wave = tid >> 6;
    const int bp = tid & 15, rq = tid >> 4;
    const int b0 = bp * 2;
    const int xb = tid >> 3, xk = (tid & 7) << 2;

    float acc[2][8];
    #pragma unroll
    for (int i = 0; i < 2; ++i)
        #pragma unroll
        for (int j = 0; j < 8; ++j) acc[i][j] = 0.f;

    auto wsel = [&](int k0, const float*& wb, int& wstr, int& wcol) {
        if (isA) { if (k0 < 768)  { wb = p.WihA; wstr = 768;  wcol = k0; }
                   else           { wb = p.WhhA; wstr = 1024; wcol = k0 - 768; } }
        else     { if (k0 < 1536) { wb = p.WihD; wstr = 1536; wcol = k0; }
                   else           { wb = p.WhhD; wstr = 1024; wcol = k0 - 1536; } }
    };
    auto xsel = [&](int k0, const float*& xs, int& xstr, int& xcol) {
        if (isA) {
            if (k0 < 256)       { xs = preT; xstr = 256;  xcol = k0; }
            else if (k0 < 768)  { xs = ctxc; xstr = 512;  xcol = k0 - 256; }
            else                { xs = hAc;  xstr = 1024; xcol = k0 - 768; }
        } else {
            if (k0 < 1024)      { xs = hAc;  xstr = 1024; xcol = k0; }
            else if (k0 < 1536) { xs = ctxc; xstr = 512;  xcol = k0 - 1024; }
            else                { xs = hDp;  xstr = 1024; xcol = k0 - 1536; }
        }
    };
    auto issueW = [&](int buf, int c) {
        int k0 = ks * kseg + c * 32;
        const float* wb; int wstr, wcol;
        wsel(k0, wb, wstr, wcol);
        int colsw = (lane & 7) << 2;
        int rbase = rt * 128 + wave * 32 + (lane >> 3);
        float* l = sh->g.W[buf] + wave * 1024;
        #pragma unroll
        for (int i = 0; i < 4; ++i) {
            int xorv = ((wave * 4 + i) & 3) << 2;
            const float* g = wb + (size_t)(rbase + i * 8) * wstr + wcol + (colsw ^ xorv);
            gl_lds16(g, l + i * 256);
        }
    };
    auto loadX = [&](int c) -> float4 {
        int k0 = ks * kseg + c * 32;
        const float* xs; int xstr, xcol;
        xsel(k0, xs, xstr, xcol);
        return *reinterpret_cast<const float4*>(xs + (size_t)xb * xstr + xcol + xk);
    };
    auto writeX = [&](int buf, float4 v) {
        *reinterpret_cast<float4*>(&sh->g.X[buf][xb * 33 + xk]) = v;
    };
    auto compute = [&](int buf) {
        const float* Wb = sh->g.W[buf];
        const float* Xb = sh->g.X[buf];
        const int rxor = (rq & 3) << 2;
        #pragma unroll
        for (int q = 0; q < 8; ++q) {
            float4 x0 = *reinterpret_cast<const float4*>(&Xb[b0 * 33 + (q << 2)]);
            float4 x1 = *reinterpret_cast<const float4*>(&Xb[(b0 + 1) * 33 + (q << 2)]);
            #pragma unroll
            for (int j = 0; j < 8; ++j) {
                float4 w = *reinterpret_cast<const float4*>(
                    &Wb[(rq * 8 + j) * 32 + ((q << 2) ^ rxor)]);
                acc[0][j] = fmaf(x0.x, w.x, fmaf(x0.y, w.y, fmaf(x0.z, w.z, fmaf(x0.w, w.w, acc[0][j]))));
                acc[1][j] = fmaf(x1.x, w.x, fmaf(x1.y, w.y, fmaf(x1.z, w.z, fmaf(x1.w, w.w, acc[1][j]))));
            }
        }
    };

    // prolog: chunk 0
    issueW(0, 0);
    float4 xv = loadX(0);
    asm volatile("s_waitcnt vmcnt(0)" ::: "memory");
    writeX(0, xv);
    __syncthreads();
    for (int c = 0; c < nc; ++c) {
        int cb = c & 1, nb = cb ^ 1;
        float4 xn;
        bool more = (c + 1 < nc);
        if (more) { issueW(nb, c + 1); xn = loadX(c + 1); }
        compute(cb);
        __syncthreads();                         // all done reading buf cb / prev writes
        if (more) {
            asm volatile("s_waitcnt vmcnt(0)" ::: "memory");
            writeX(nb, xn);
        }
        __syncthreads();                         // next buffer published
    }
    // write partials
    float* q0 = (isA ? p.partA : p.partD) +
                ((size_t)(ks * 32 + b0) * 4096 + rt * 128 + rq * 8);
    *reinterpret_cast<float4*>(q0)     = make_float4(acc[0][0], acc[0][1], acc[0][2], acc[0][3]);
    *reinterpret_cast<float4*>(q0 + 4) = make_float4(acc[0][4], acc[0][5], acc[0][6], acc[0][7]);
    float* q1 = q0 + 4096;
    *reinterpret_cast<float4*>(q1)     = make_float4(acc[1][0], acc[1][1], acc[1][2], acc[1][3]);
    *reinterpret_cast<float4*>(q1 + 4) = make_float4(acc[1][4], acc[1][5], acc[1][6], acc[1][7]);
}

// ---------------- phase 2: gates+proj | gates+attn(softmax) | prenet -------
__device__ void phase2(const P& p, SHU* sh, int t) {
    const int tid = threadIdx.x;
    const int blk = blockIdx.x;
    int pc = t & 1, pn = (t + 1) & 1;
    if (blk < 32) {
        // ---- D-gates + proj(t) ----
        if (t < 0) return;
        int b = blk;
        float* hDn = pc ? p.hD1 : p.hD0;
        const float* ctxc = pc ? p.ctx1 : p.ctx0;
        for (int j = 0; j < 4; ++j) {
            int u = tid + (j << 8);
            float z[4];
            #pragma unroll
            for (int g2 = 0; g2 < 4; ++g2) {
                float s = p.bD[g2 * 1024 + u];
                #pragma unroll
                for (int ks = 0; ks < NKD; ++ks)
                    s += p.partD[(size_t)(ks * 32 + b) * 4096 + g2 * 1024 + u];
                z[g2] = s;
            }
            int idx = b * 1024 + u;
            float cn = sigf(z[1]) * p.cD[idx] + sigf(z[0]) * tanhf(z[2]);
            float hn = sigf(z[3]) * tanhf(cn);
            p.cD[idx] = cn; hDn[idx] = hn; sh->p.hc[u] = hn;
        }
        for (int k = tid; k < 512; k += 256) sh->p.hc[1024 + k] = ctxc[(size_t)b * 512 + k];
        __syncthreads();
        if (tid < 162) {
            int o = tid >> 1, hf = tid & 1;
            const float* wr = (o < 80) ? (p.Wp + (size_t)o * 1536) : p.Wg;
            float s = 0.f;
            int k0 = hf * 768;
            for (int k = k0; k < k0 + 768; k += 4) {
                float4 w = *reinterpret_cast<const float4*>(wr + k);
                s = fmaf(sh->p.hc[k], w.x, s);   s = fmaf(sh->p.hc[k+1], w.y, s);
                s = fmaf(sh->p.hc[k+2], w.z, s); s = fmaf(sh->p.hc[k+3], w.w, s);
            }
            sh->p.redp[tid] = s;
        }
        __syncthreads();
        if (tid < 81) {
            float s = sh->p.redp[2 * tid] + sh->p.redp[2 * tid + 1];
            if (tid < 80) p.mel[((size_t)b * T_DEC + t) * 80 + tid] = s + p.bp[tid];
            else          p.gate[(size_t)b * T_DEC + t] = s + p.bg[0];
        }
    } else if (blk < 64) {
        // ---- A-gates + attn(t+1) through softmax ----
        if (t < -1 || t >= 255) return;
        int b = blk - 32, tt = t + 1;
        float* hAn = pn ? p.hA1 : p.hA0;
        // re-stage attn weights (LDS was clobbered by phase1)
        for (int i = tid; i < 992; i += 256) {
            int k = i >> 5, f = i & 31;
            sh->a.wlc0[k][f] = p.Wlc[(size_t)f * 62 + k];
            sh->a.wlc1[k][f] = p.Wlc[(size_t)f * 62 + 31 + k];
        }
        for (int i = tid; i < 4096; i += 256) sh->a.wlds[i >> 5][i & 31] = p.Wld[i];
        if (tid < 128) sh->a.vs[tid] = p.vatt[tid];
        // A-gates
        for (int j = 0; j < 4; ++j) {
            int u = tid + (j << 8);
            float z[4];
            #pragma unroll
            for (int g2 = 0; g2 < 4; ++g2) {
                float s = p.bA[g2 * 1024 + u];
                #pragma unroll
                for (int ks = 0; ks < NKA; ++ks)
                    s += p.partA[(size_t)(ks * 32 + b) * 4096 + g2 * 1024 + u];
                z[g2] = s;
            }
            int idx = b * 1024 + u;
            float cn = sigf(z[1]) * p.cA[idx] + sigf(z[0]) * tanhf(z[2]);
            float hn = sigf(z[3]) * tanhf(cn);
            p.cA[idx] = cn; hAn[idx] = hn; sh->a.hs[u] = hn;
        }
        for (int i = tid; i < 288; i += 256) {
            int pos = i - 16;
            float v0 = 0.f, v1 = 0.f;
            if (pos >= 0 && pos < 256) {
                v0 = p.aw[(size_t)b * 256 + pos];
                v1 = p.cum[(size_t)b * 256 + pos];
            }
            sh->a.aw0s[i] = v0; sh->a.aw1s[i] = v1;
        }
        __syncthreads();
        // pq
        {
            int d = tid & 127, hf = tid >> 7;
            float s = 0.f;
            int k0 = hf * 512;
            for (int k = k0; k < k0 + 512; ++k)
                s = fmaf(sh->a.hs[k], p.wqT[(size_t)k * 128 + d], s);
            sh->a.red[tid] = s;
        }
        __syncthreads();
        if (tid < 128) sh->a.pqs[tid] = sh->a.red[tid] + sh->a.red[tid + 128];
        __syncthreads();
        // conv (per enc position tid)
        float cf[32];
        #pragma unroll
        for (int f = 0; f < 32; ++f) cf[f] = 0.f;
        for (int k = 0; k < 31; ++k) {
            float a0 = sh->a.aw0s[tid + 1 + k], a1 = sh->a.aw1s[tid + 1 + k];
            #pragma unroll
            for (int fq = 0; fq < 8; ++fq) {
                float4 w0 = *reinterpret_cast<const float4*>(&sh->a.wlc0[k][fq << 2]);
                float4 w1 = *reinterpret_cast<const float4*>(&sh->a.wlc1[k][fq << 2]);
                cf[fq*4+0] = fmaf(a0, w0.x, fmaf(a1, w1.x, cf[fq*4+0]));
                cf[fq*4+1] = fmaf(a0, w0.y, fmaf(a1, w1.y, cf[fq*4+1]));
                cf[fq*4+2] = fmaf(a0, w0.z, fmaf(a1, w1.z, cf[fq*4+2]));
                cf[fq*4+3] = fmaf(a0, w0.w, fmaf(a1, w1.w, cf[fq*4+3]));
            }
        }
        // energies
        float e = 0.f;
        {
            const float* pmr = p.pm + ((size_t)b * 256 + tid) * 128;
            for (int d = 0; d < 128; ++d) {
                float loc = 0.f;
                #pragma unroll
                for (int fq = 0; fq < 8; ++fq) {
                    float4 w = *reinterpret_cast<const float4*>(&sh->a.wlds[d][fq << 2]);
                    loc = fmaf(cf[fq*4+0], w.x, loc); loc = fmaf(cf[fq*4+1], w.y, loc);
                    loc = fmaf(cf[fq*4+2], w.z, loc); loc = fmaf(cf[fq*4+3], w.w, loc);
                }
                float a = tanhf(sh->a.pqs[d] + loc + pmr[d]);
                e = fmaf(a, sh->a.vs[d], e);
            }
        }
        if (tid >= p.mlen[b]) e = -1e9f;
        // softmax over 256
        float m = e;
        #pragma unroll
        for (int o2 = 32; o2 >= 1; o2 >>= 1) m = fmaxf(m, __shfl_xor(m, o2));
        if ((tid & 63) == 0) sh->a.red4[tid >> 6] = m;
        __syncthreads();
        m = fmaxf(fmaxf(sh->a.red4[0], sh->a.red4[1]),
                  fmaxf(sh->a.red4[2], sh->a.red4[3]));
        __syncthreads();
        float pe = expf(e - m);
        float s = pe;
        #pragma unroll
        for (int o2 = 32; o2 >= 1; o2 >>= 1) s += __shfl_xor(s, o2);
        if ((tid & 63) == 0) sh->a.red4[tid >> 6] = s;
        __syncthreads();
        s = sh->a.red4[0] + sh->a.red4[1] + sh->a.red4[2] + sh->a.red4[3];
        float w = pe / s;
        p.aw[(size_t)b * 256 + tid] = w;
        p.cum[(size_t)b * 256 + tid] += w;
        p.align[((size_t)b * T_DEC + tt) * 256 + tid] = w;
    } else if (blk < 96) {
        // ---- prenet(t+2) ----
        int ts = t + 2;
        if (ts > 255) return;
        int b = blk - 64;
        float* dst = (ts & 1) ? p.preB1 : p.preB0;
        if (tid < 80) sh->n.xs[tid] = (ts == 0) ? 0.0f
                        : p.inputs[((size_t)b * T_DEC + (ts - 1)) * 80 + tid];
        __syncthreads();
        {
            const float* wr = p.Wpre1 + (size_t)tid * 80;
            float s = 0.f;
            #pragma unroll 8
            for (int k = 0; k < 80; ++k) s = fmaf(sh->n.xs[k], wr[k], s);
            sh->n.h1[tid] = fmaxf(s, 0.0f);
        }
        __syncthreads();
        {
            const float* wr = p.Wpre2 + (size_t)tid * 256;
            float s = 0.f;
            for (int k = 0; k < 256; k += 4) {
                float4 w = *reinterpret_cast<const float4*>(wr + k);
                s = fmaf(sh->n.h1[k], w.x, s);   s = fmaf(sh->n.h1[k+1], w.y, s);
                s = fmaf(sh->n.h1[k+2], w.z, s); s = fmaf(sh->n.h1[k+3], w.w, s);
            }
            dst[(size_t)b * 256 + tid] = fmaxf(s, 0.0f);
        }
    }
}

// ---------------- phase 3: ctx(t+1) spread over 256 blocks -----------------
__device__ void phase3(const P& p, SHU* sh, int t) {
    const int blk = blockIdx.x;
    if (blk < 96 || blk >= 352 || t >= 255) return;
    const int tid = threadIdx.x;
    int idx = blk - 96;                 // 0..255
    int b = idx >> 3, d0 = (idx & 7) << 6;
    float* ctxn = ((t + 1) & 1) ? p.ctx1 : p.ctx0;
    for (int i = tid; i < 256; i += 256) sh->c.sm[i] = p.aw[(size_t)b * 256 + i];
    __syncthreads();
    int lane = tid & 63, w = tid >> 6;
    const float* e = p.enc + (size_t)b * 131072 + d0 + lane;
    float a0 = 0.f, a1 = 0.f, a2 = 0.f, a3 = 0.f;
    int tb = w * 64;
    #pragma unroll 4
    for (int j = 0; j < 64; j += 4) {
        a0 = fmaf(sh->c.sm[tb + j],     e[(size_t)(tb + j) * 512],     a0);
        a1 = fmaf(sh->c.sm[tb + j + 1], e[(size_t)(tb + j + 1) * 512], a1);
        a2 = fmaf(sh->c.sm[tb + j + 2], e[(size_t)(tb + j + 2) * 512], a2);
        a3 = fmaf(sh->c.sm[tb + j + 3], e[(size_t)(tb + j + 3) * 512], a3);
    }
    sh->c.red[w][lane] = (a0 + a1) + (a2 + a3);
    __syncthreads();
    if (tid < 64)
        ctxn[(size_t)b * 512 + d0 + tid] = (sh->c.red[0][tid] + sh->c.red[1][tid])
                                         + (sh->c.red[2][tid] + sh->c.red[3][tid]);
}

// ---------------- persistent cooperative kernel ----------------
__global__ __launch_bounds__(256, 2) void coop_main(P p) {
    cg::grid_group g = cg::this_grid();
    __shared__ SHU sh;
    phase2(p, &sh, -2);            // prenet(0) only
    g.sync();
    for (int t = -1; t <= 255; ++t) {
        phase1(p, &sh, t);
        g.sync();
        phase2(p, &sh, t);
        g.sync();
        if (t < 255) {
            phase3(p, &sh, t);
            g.sync();
        }
    }
}

// ---------------- discrete fallback ----------------
__global__ __launch_bounds__(256, 2) void fb1(P p, int t) { __shared__ SHU sh; phase1(p, &sh, t); }
__global__ __launch_bounds__(256)    void fb2(P p, int t) { __shared__ SHU sh; phase2(p, &sh, t); }
__global__ __launch_bounds__(256)    void fb3(P p, int t) { __shared__ SHU sh; phase3(p, &sh, t); }

// ---------------- host ----------------
extern "C" void kernel_launch(void* const* d_in, const int* in_sizes, int n_in,
                              void* d_out, int out_size, void* d_ws, size_t ws_size,
                              hipStream_t stream) {
    const float* enc    = (const float*)d_in[0];
    const float* inputs = (const float*)d_in[1];
    const void*  mlraw  = d_in[2];
    const float* W_pre1 = (const float*)d_in[3];
    const float* W_pre2 = (const float*)d_in[4];
    const float* Wih_a  = (const float*)d_in[5];
    const float* Whh_a  = (const float*)d_in[6];
    const float* b_a    = (const float*)d_in[7];
    const float* W_q    = (const float*)d_in[8];
    const float* W_mem  = (const float*)d_in[9];
    const float* Wlc    = (const float*)d_in[10];
    const float* Wld    = (const float*)d_in[11];
    const float* v_att  = (const float*)d_in[12];
    const float* Wih_d  = (const float*)d_in[13];
    const float* Whh_d  = (const float*)d_in[14];
    const float* b_d    = (const float*)d_in[15];
    const float* W_proj = (const float*)d_in[16];
    const float* b_proj = (const float*)d_in[17];
    const float* W_gate = (const float*)d_in[18];
    const float* b_gate = (const float*)d_in[19];

    float* ws = (float*)d_ws;
    size_t o = 0;
    float* pm    = ws + o; o += 1048576;
    float* wqT   = ws + o; o += 131072;
    float* preB0 = ws + o; o += 8192;
    float* preB1 = ws + o; o += 8192;
    size_t zs0 = o;
    float* hA0 = ws + o; o += 32768;
    float* hA1 = ws + o; o += 32768;
    float* cA  = ws + o; o += 32768;
    float* hD0 = ws + o; o += 32768;
    float* hD1 = ws + o; o += 32768;
    float* cD  = ws + o; o += 32768;
    float* aw  = ws + o; o += 8192;
    float* cum = ws + o; o += 8192;
    float* ctx0 = ws + o; o += 16384;
    float* ctx1 = ws + o; o += 16384;
    int zlen = (int)(o - zs0);                    // 245760
    float* partA = ws + o; o += (size_t)NKA * 32 * 4096;   // 917504
    float* partD = ws + o; o += (size_t)NKD * 32 * 4096;   // 1048576
    int* mlen = (int*)(ws + o); o += 32;
    if (ws_size < o * 4) return;                  // diagnostic: 0.1455 signature

    float* out       = (float*)d_out;
    float* mel_out   = out;
    float* gate_out  = out + (size_t)32 * 256 * 80;
    float* align_out = gate_out + (size_t)32 * 256;

    convert_mlen<<<1, 32, 0, stream>>>(mlraw, mlen);
    proc_mem<<<8192, 128, 0, stream>>>(enc, W_mem, pm);
    transpose_wq<<<512, 256, 0, stream>>>(W_q, wqT);
    zero_f<<<(zlen + 255) / 256, 256, 0, stream>>>(ws + zs0, zlen);

    P pv;
    pv.WihA = Wih_a; pv.WhhA = Whh_a; pv.bA = b_a;
    pv.WihD = Wih_d; pv.WhhD = Whh_d; pv.bD = b_d;
    pv.enc = enc; pv.pm = pm; pv.wqT = wqT;
    pv.Wlc = Wlc; pv.Wld = Wld; pv.vatt = v_att;
    pv.Wp = W_proj; pv.bp = b_proj; pv.Wg = W_gate; pv.bg = b_gate;
    pv.inputs = inputs; pv.Wpre1 = W_pre1; pv.Wpre2 = W_pre2;
    pv.preB0 = preB0; pv.preB1 = preB1;
    pv.hA0 = hA0; pv.hA1 = hA1; pv.cA = cA;
    pv.hD0 = hD0; pv.hD1 = hD1; pv.cD = cD;
    pv.aw = aw; pv.cum = cum; pv.ctx0 = ctx0; pv.ctx1 = ctx1;
    pv.partA = partA; pv.partD = partD;
    pv.mlen = mlen;
    pv.mel = mel_out; pv.gate = gate_out; pv.align = align_out;

    void* args[] = { &pv };
    hipError_t e = hipLaunchCooperativeKernel((const void*)coop_main,
                                              dim3(NBLK), dim3(256), args, 0, stream);
    if (e != hipSuccess) {
        fb2<<<96, 256, 0, stream>>>(pv, -2);
        for (int t = -1; t <= 255; ++t) {
            fb1<<<NBLK, 256, 0, stream>>>(pv, t);
            fb2<<<96, 256, 0, stream>>>(pv, t);
            if (t < 255) fb3<<<352, 256, 0, stream>>>(pv, t);
        }
    }
}